// Round 7
// baseline (1019.771 us; speedup 1.0000x reference)
//
#include <hip/hip_runtime.h>
#include <math.h>

// DifferentiableRiskBudgeting: B=512, P=256. One block (256 thr) per batch.
// Thread (ti=tid>>2, tj=tid&3) owns rows 4ti..4ti+3 x cols 64tj..64tj+63.
//   Rows +0..2: fp32 VGPRs as <2 x float> pairs.
//   Row  +3: fp32 LDS slab, stride 272 + tj-stride 68 (conflict-free b128).
// R7: matvec FMAs forced to v_pk_fma_f32 via inline asm (testing the
// hypothesis that builtin elementwise fma scalarized — would explain the
// ~2.3x VALU inst inflation measured in R5/R6).
// Structural note: fp32-register-resident sigma (192 regs/wave) caps
// occupancy at 2 blocks/CU regardless of LDS; optimizing inst count is the
// remaining lever.
// One barrier per PGD iteration (wave-local w copies, double-buffered stage).
// Projection: 10-round Illinois regula-falsi, v_rcp_f32 secant.

#define PP    256
#define MAXW  0.1f
#define EPSF  1e-8f
#define NPGD  250
#define NPOW  20
#define NILL  10

#define R3S   272   // sigma row-3 slab stride (floats); 272 % 32 == 16
#define TJS   68    // tj stride inside slab row;        68 % 32 == 4
#define WRDS  72    // w-copy block stride (64 data + 8 stagger)
#define VCOPY 280   // per-wave w copy stride

typedef float v2 __attribute__((ext_vector_type(2)));
typedef float v4t __attribute__((ext_vector_type(4)));

__device__ __forceinline__ void pkfma(v2& acc, v2 a, v2 b) {
    asm volatile("v_pk_fma_f32 %0, %1, %2, %0"
                 : "+v"(acc)
                 : "v"(a), "v"(b));
}

template<int CTRL>
__device__ __forceinline__ float dpp_zero(float x) {
    return __int_as_float(__builtin_amdgcn_update_dpp(
        0, __float_as_int(x), CTRL, 0xF, 0xF, true));
}
template<int CTRL>
__device__ __forceinline__ float dpp_keep(float x) {
    int xi = __float_as_int(x);
    return __int_as_float(__builtin_amdgcn_update_dpp(xi, xi, CTRL, 0xF, 0xF, false));
}
__device__ __forceinline__ float rdlane63(float x) {
    return __int_as_float(__builtin_amdgcn_readlane(__float_as_int(x), 63));
}
__device__ __forceinline__ float wave_sum63(float s) {
    s += dpp_zero<0x111>(s);
    s += dpp_zero<0x112>(s);
    s += dpp_zero<0x114>(s);
    s += dpp_zero<0x118>(s);
    s += dpp_zero<0x142>(s);
    s += dpp_zero<0x143>(s);
    return s;
}
__device__ __forceinline__ float wave_min63(float m) {
    m = fminf(m, dpp_keep<0x111>(m));
    m = fminf(m, dpp_keep<0x112>(m));
    m = fminf(m, dpp_keep<0x114>(m));
    m = fminf(m, dpp_keep<0x118>(m));
    m = fminf(m, dpp_keep<0x142>(m));
    m = fminf(m, dpp_keep<0x143>(m));
    return m;
}
__device__ __forceinline__ float wave_max63(float m) {
    m = fmaxf(m, dpp_keep<0x111>(m));
    m = fmaxf(m, dpp_keep<0x112>(m));
    m = fmaxf(m, dpp_keep<0x114>(m));
    m = fmaxf(m, dpp_keep<0x118>(m));
    m = fmaxf(m, dpp_keep<0x142>(m));
    m = fmaxf(m, dpp_keep<0x143>(m));
    return m;
}

__global__ __launch_bounds__(256)
__attribute__((amdgpu_waves_per_eu(2, 2)))
void drb_kernel(const float* __restrict__ sigma,
                const float* __restrict__ beta,
                const float* __restrict__ wprev,
                const float* __restrict__ pl1,
                const float* __restrict__ pl2,
                float* __restrict__ out)
{
    const int b    = blockIdx.x;
    const int tid  = threadIdx.x;
    const int lane = tid & 63;
    const int wv   = tid >> 6;
    const int ti   = tid >> 2;   // 0..63
    const int tj   = tid & 3;    // 0..3

    __shared__ __align__(16) float sigR3[64 * R3S];   // 69632 B
    __shared__ __align__(16) float wcop[4 * VCOPY];   //  4480 B
    __shared__ __align__(16) float stage[2][256];     //  2048 B

    const float* Sb = sigma + (size_t)b * (PP * PP);

    // ---- stage sigma: rows +0..2 -> v2 VGPR pairs; row +3 -> LDS slab
    v2 s0[32], s1[32], s2[32];
    {
        const float* r0 = Sb + (4 * ti + 0) * PP + 64 * tj;
        const float* r1 = Sb + (4 * ti + 1) * PP + 64 * tj;
        const float* r2 = Sb + (4 * ti + 2) * PP + 64 * tj;
#pragma unroll
        for (int k = 0; k < 16; ++k) {
            v4t t0 = *(const v4t*)(r0 + 4 * k);
            v4t t1 = *(const v4t*)(r1 + 4 * k);
            v4t t2 = *(const v4t*)(r2 + 4 * k);
            s0[2*k]   = __builtin_shufflevector(t0, t0, 0, 1);
            s0[2*k+1] = __builtin_shufflevector(t0, t0, 2, 3);
            s1[2*k]   = __builtin_shufflevector(t1, t1, 0, 1);
            s1[2*k+1] = __builtin_shufflevector(t1, t1, 2, 3);
            s2[2*k]   = __builtin_shufflevector(t2, t2, 0, 1);
            s2[2*k+1] = __builtin_shufflevector(t2, t2, 2, 3);
        }
        const float* r3 = Sb + (4 * ti + 3) * PP + 64 * tj;
        float* d3 = sigR3 + ti * R3S + TJS * tj;
#pragma unroll
        for (int k = 0; k < 16; ++k)
            *(v4t*)(d3 + 4 * k) = *(const v4t*)(r3 + 4 * k);
        // row-3 slab is written and read by the SAME thread -> no barrier.
    }

    const float bt   = beta[b * PP + tid];
    const float wp   = wprev[b * PP + tid];
    const float lam1 = expf(pl1[0]);
    const float lam2 = expf(pl2[0]);

    float* wme = wcop + wv * VCOPY;                // my wave's full-vector copy
    const int wst = 4 * lane + 8 * (lane >> 4);    // staggered write slot
    const float* wrd = wme + WRDS * tj;            // matvec read base (72*tj)

    // y = Sigma * w (w from my wave's copy); returns y[row tid]
    auto matvec = [&]() -> float {
        v2 y0 = {0.f, 0.f}, y1 = {0.f, 0.f}, y2 = {0.f, 0.f}, y3 = {0.f, 0.f};
        const float* p3 = sigR3 + ti * R3S + TJS * tj;
#pragma unroll
        for (int k = 0; k < 16; ++k) {
            v4t wq = *(const v4t*)(wrd + 4 * k);
            v2 w01 = __builtin_shufflevector(wq, wq, 0, 1);
            v2 w23 = __builtin_shufflevector(wq, wq, 2, 3);
            pkfma(y0, s0[2*k],   w01);
            pkfma(y0, s0[2*k+1], w23);
            pkfma(y1, s1[2*k],   w01);
            pkfma(y1, s1[2*k+1], w23);
            pkfma(y2, s2[2*k],   w01);
            pkfma(y2, s2[2*k+1], w23);
            v4t q = *(const v4t*)(p3 + 4 * k);
            v2 q01 = __builtin_shufflevector(q, q, 0, 1);
            v2 q23 = __builtin_shufflevector(q, q, 2, 3);
            pkfma(y3, q01, w01);
            pkfma(y3, q23, w23);
        }
        float r0 = y0.x + y0.y, r1 = y1.x + y1.y;
        float r2 = y2.x + y2.y, r3 = y3.x + y3.y;
        r0 += dpp_zero<0x4E>(r0); r1 += dpp_zero<0x4E>(r1);
        r2 += dpp_zero<0x4E>(r2); r3 += dpp_zero<0x4E>(r3);
        r0 += dpp_zero<0xB1>(r0); r1 += dpp_zero<0xB1>(r1);
        r2 += dpp_zero<0xB1>(r2); r3 += dpp_zero<0xB1>(r3);
        float a01 = (tj & 1) ? r1 : r0;
        float a23 = (tj & 1) ? r3 : r2;
        return (tj & 2) ? a23 : a01;
    };

    // ---- power iteration: each wave's copy initialized to 1/16 (wave-local)
    {
        v4t c = {0.0625f, 0.0625f, 0.0625f, 0.0625f};
        *(v4t*)(wme + wst) = c;
    }

    float y_last = 0.f, a_last = 1.f;
#pragma unroll 1
    for (int pi = 0; pi < NPOW; ++pi) {
        float y = matvec();
        stage[pi & 1][tid] = y;
        __syncthreads();
        v4t u4 = *(const v4t*)(&stage[pi & 1][4 * lane]);
        float ss = fmaf(u4.x, u4.x, fmaf(u4.y, u4.y, fmaf(u4.z, u4.z, u4.w * u4.w)));
        float a  = 1.f / (sqrtf(rdlane63(wave_sum63(ss))) + EPSF);
        v4t n4 = {a * u4.x, a * u4.y, a * u4.z, a * u4.w};
        *(v4t*)(wme + wst) = n4;          // full normalized vector, my copy
        y_last = y; a_last = a;
    }

    // ---- lmax = v' S v ; step
    float stepf;
    {
        float ysv = matvec();
        float p   = (a_last * y_last) * ysv;
        stage[0][tid] = p;
        __syncthreads();
        v4t p4 = *(const v4t*)(&stage[0][4 * lane]);
        float lmax = rdlane63(wave_sum63((p4.x + p4.y) + (p4.z + p4.w)));
        stepf = 1.f / (2.f * lmax + 2.f * lam2 + 1e-6f);
        __syncthreads();   // everyone done with stage[0] before PGD reuses it
    }

    // ---- PGD init: w0 = 1/256 (wave-local full copy)
    float w_own = 1.f / 256.f;
    {
        v4t c = {1.f/256.f, 1.f/256.f, 1.f/256.f, 1.f/256.f};
        *(v4t*)(wme + wst) = c;
    }
    const float Ac = 1.f - 2.f * lam2 * stepf;
    const float Bc = -2.f * stepf;
    const float Cc = stepf * (bt - lam1 + 2.f * lam2 * wp);

#pragma unroll 1
    for (int it = 0; it < NPGD; ++it) {
        float y = matvec();
        float v_own = fmaf(w_own, Ac, fmaf(y, Bc, Cc));
        const int sb = it & 1;
        stage[sb][tid] = v_own;
        __syncthreads();                      // the ONLY barrier this iteration

        v4t v4 = *(const v4t*)(&stage[sb][4 * lane]);
        float mn = rdlane63(wave_min63(fminf(fminf(v4.x, v4.y), fminf(v4.z, v4.w))));
        float mx = rdlane63(wave_max63(fmaxf(fmaxf(v4.x, v4.y), fmaxf(v4.z, v4.w))));

        // Illinois regula-falsi on f(tau)=s(tau)-1; known bracket values:
        //   s(mn-MAXW)=256*MAXW, s(mx)=0
        float lo = mn - MAXW, flo = 256.f * MAXW - 1.f;
        float hi = mx,        fhi = -1.f;
        int side = 0;
        float tau = 0.f;
#pragma unroll 1
        for (int r = 0; r < NILL; ++r) {
            tau = (lo * fhi - hi * flo) * __builtin_amdgcn_rcpf(fhi - flo);
            float c0 = __builtin_amdgcn_fmed3f(v4.x - tau, 0.f, MAXW);
            float c1 = __builtin_amdgcn_fmed3f(v4.y - tau, 0.f, MAXW);
            float c2 = __builtin_amdgcn_fmed3f(v4.z - tau, 0.f, MAXW);
            float c3 = __builtin_amdgcn_fmed3f(v4.w - tau, 0.f, MAXW);
            float f = rdlane63(wave_sum63((c0 + c1) + (c2 + c3))) - 1.f;
            bool pos = f > 0.f;
            float nflo = pos ? f   : ((side < 0) ? 0.5f * flo : flo);
            float nfhi = pos ? ((side > 0) ? 0.5f * fhi : fhi) : f;
            lo  = pos ? tau : lo;
            hi  = pos ? hi  : tau;
            flo = nflo; fhi = nfhi;
            side = pos ? 1 : -1;
        }
        tau = (lo * fhi - hi * flo) * __builtin_amdgcn_rcpf(fhi - flo);

        v4t w4 = {__builtin_amdgcn_fmed3f(v4.x - tau, 0.f, MAXW),
                  __builtin_amdgcn_fmed3f(v4.y - tau, 0.f, MAXW),
                  __builtin_amdgcn_fmed3f(v4.z - tau, 0.f, MAXW),
                  __builtin_amdgcn_fmed3f(v4.w - tau, 0.f, MAXW)};
        *(v4t*)(wme + wst) = w4;              // full projected w, my wave's copy
        w_own = __builtin_amdgcn_fmed3f(v_own - tau, 0.f, MAXW);
    }

    // ---- renormalize + store
    stage[0][tid] = w_own;
    __syncthreads();
    v4t w4 = *(const v4t*)(&stage[0][4 * lane]);
    float S = rdlane63(wave_sum63((w4.x + w4.y) + (w4.z + w4.w)));
    out[b * PP + tid] = w_own / (S + EPSF);
}

extern "C" void kernel_launch(void* const* d_in, const int* in_sizes, int n_in,
                              void* d_out, int out_size, void* d_ws, size_t ws_size,
                              hipStream_t stream) {
    const float* sigma  = (const float*)d_in[0];
    const float* beta   = (const float*)d_in[1];
    const float* wprevp = (const float*)d_in[2];
    const float* pl1    = (const float*)d_in[3];
    const float* pl2    = (const float*)d_in[4];
    float* outp = (float*)d_out;
    drb_kernel<<<dim3(512), dim3(256), 0, stream>>>(sigma, beta, wprevp, pl1, pl2, outp);
}